// Round 8
// baseline (450.012 us; speedup 1.0000x reference)
//
#include <hip/hip_runtime.h>
#include <math.h>

#define T_LEN 4096
#define B_SZ  512
#define RP 68   // delta LDS row pitch (dwords): 16B-aligned, 2-way-bank (free)

// emission: fl(fl(fl(-0.5*x)*x) - fl32(0.5*log(2*pi)))
__device__ __forceinline__ float emis(float xv) {
    float a = __fmul_rn(-0.5f, xv);
    float b = __fmul_rn(a, xv);
    return __fsub_rn(b, (float)0.9189385332046727);
}

// ---------------------------------------------------------------------------
// Fused prep+emit. Block 0 computes logA (numpy pairwise-16 rowsum, fp64 log
// rounded to fp32) and logAT; all blocks compute E = emis(x).
__global__ __launch_bounds__(256) void k_emit(const float* __restrict__ x,
                                              float* __restrict__ E,
                                              const float* __restrict__ hmm,
                                              float* __restrict__ logA,
                                              float* __restrict__ logAT) {
    int tid = threadIdx.x;
    if (blockIdx.x == 0) {
        int i = tid >> 4, j = tid & 15;
        const float* row = hmm + i * 16;
        float r[8];
#pragma unroll
        for (int k = 0; k < 8; ++k) r[k] = __fadd_rn(row[k], row[k + 8]);
        float s = __fadd_rn(
            __fadd_rn(__fadd_rn(r[0], r[1]), __fadd_rn(r[2], r[3])),
            __fadd_rn(__fadd_rn(r[4], r[5]), __fadd_rn(r[6], r[7])));
        float la = (float)log((double)row[j]);
        float ls = (float)log((double)s);
        float v = __fsub_rn(la, ls);
        logA[tid] = v;
        logAT[j * 16 + i] = v;
    }
    int i = blockIdx.x * 256 + tid;
    float4 v = ((const float4*)x)[i];
    float4 e;
    e.x = emis(v.x); e.y = emis(v.y); e.z = emis(v.z); e.w = emis(v.w);
    ((float4*)E)[i] = e;
}

// ---------------------------------------------------------------------------
#define DPP_ROR0(K, SRC) __builtin_amdgcn_update_dpp(0, (SRC), 0x120 + (K), 0xF, 0xF, false)
#define M3(x, y, z) fmaxf(fmaxf(x, y), z)

#define ADDPP(DST, K)                                                                 \
    asm("v_add_f32_dpp %0, %1, %2 row_ror:" #K " row_mask:0xf bank_mask:0xf"          \
        : "=v"(DST) : "v"(d), "v"(a[K]))

#define STEPC(ET)                                                                     \
    {                                                                                 \
        float s0 = __fadd_rn(d, a[0]);                                                \
        float s1, s2, s3, s4, s5, s6, s7, s8, s9, s10, s11, s12, s13, s14, s15;       \
        ADDPP(s1, 1);   ADDPP(s2, 2);   ADDPP(s3, 3);   ADDPP(s4, 4);                 \
        ADDPP(s5, 5);   ADDPP(s6, 6);   ADDPP(s7, 7);   ADDPP(s8, 8);                 \
        ADDPP(s9, 9);   ADDPP(s10, 10); ADDPP(s11, 11); ADDPP(s12, 12);               \
        ADDPP(s13, 13); ADDPP(s14, 14); ADDPP(s15, 15);                               \
        float u0 = M3(s0, s1, s2),  u1 = M3(s3, s4, s5),  u2 = M3(s6, s7, s8);        \
        float u3 = M3(s9, s10, s11), u4 = M3(s12, s13, s14);                          \
        float m = fmaxf(M3(u0, u1, u2), M3(u3, u4, s15));                             \
        d = __fadd_rn(m, ET);                                                         \
    }

// k_main: fwd + psi + chunk-maps pipelined inside each block.
// Wave 0: 4 Viterbi chains (R3 ADDPP structure), deltas -> LDS double buffer.
//   dbuf slot r in 0..63 = delta row 64p+1+r; slot 64 = delta row 64p.
// Waves 1-2 (phase p): psi of chunk p-1 from dbuf[(p-1)&1] -> pbuf + global.
// Wave 3 (phase p): map-walk of chunk p-2 from pbuf[(p-2)&1] -> global M.
__global__ __launch_bounds__(256) void k_main(const float* __restrict__ E,
                                              const float* __restrict__ logA,
                                              const float* __restrict__ logAT,
                                              unsigned char* __restrict__ psi,
                                              unsigned char* __restrict__ M,
                                              float* __restrict__ carry) {
    __shared__ float dbuf[2][4][16][RP];        // 34816 B
    __shared__ unsigned char pbuf[2][4][64][16]; // 8192 B
    const int tid = threadIdx.x;
    const int wave = tid >> 6;
    const int blk = blockIdx.x;

    if (wave == 0) {
        asm volatile("s_setprio 3");
        const int j = tid & 15, g = tid >> 4;
        const int b = blk * 4 + g;
        float a[16];
        a[0] = logA[j * 16 + j];
#define LOADA(K) { int sk = DPP_ROR0(K, j); a[K] = logA[sk * 16 + j]; }
        LOADA(1)  LOADA(2)  LOADA(3)  LOADA(4)  LOADA(5)
        LOADA(6)  LOADA(7)  LOADA(8)  LOADA(9)  LOADA(10)
        LOADA(11) LOADA(12) LOADA(13) LOADA(14) LOADA(15)
#undef LOADA
        const float* eb = E + b * T_LEN;
        float d = __fadd_rn(logA[j], eb[0]);   // delta row 0
        float e0 = eb[1], e1 = eb[2], e2 = eb[3], e3 = eb[4];
        int t = 1;
        for (int p = 0; p < 66; ++p) {
            __syncthreads();
            if (p < 64) {
                const int pq = p & 1;
                dbuf[pq][g][j][64] = d;        // delta row 64p
                const int nfull = (p == 63) ? 15 : 16;
                for (int k = 0; k < nfull; ++k) {
                    float4 dq;
                    STEPC(e0) dq.x = d; e0 = eb[t + 4];
                    STEPC(e1) dq.y = d; e1 = eb[t + 5];
                    STEPC(e2) dq.z = d; e2 = eb[t + 6];
                    STEPC(e3) dq.w = d; e3 = eb[t + 7];
                    *(float4*)&dbuf[pq][g][j][k << 2] = dq;
                    t += 4;
                }
                if (p == 63) {  // t = 4093..4095 -> slots 60..62
                    STEPC(e0) dbuf[pq][g][j][60] = d;
                    STEPC(e1) dbuf[pq][g][j][61] = d;
                    STEPC(e2) dbuf[pq][g][j][62] = d;
                    t += 3;
                }
            }
        }
        carry[b * 16 + j] = d;
    } else if (wave <= 2) {
        const int l = tid - 64;            // 0..127
        const int g2 = l >> 5, rr = l & 31;
        const int b2 = blk * 4 + g2;
        for (int p = 0; p < 66; ++p) {
            __syncthreads();
            if (p >= 1 && p <= 64) {
                const int c = p - 1, q = c & 1;
#pragma unroll
                for (int half = 0; half < 2; ++half) {
                    const int r = rr + half * 32;
                    const int t2 = 64 * c + 1 + r;
                    if (t2 <= T_LEN - 1) {
                        const int rs = (r == 0) ? 64 : (r - 1);  // delta row t2-1
                        float dd[16];
#pragma unroll
                        for (int i = 0; i < 16; ++i) dd[i] = dbuf[q][g2][i][rs];
                        unsigned long long pk = 0ull;
#pragma clang loop unroll(disable)
                        for (int jj = 0; jj < 16; ++jj) {
                            const float* col = logAT + (jj << 4);  // wave-uniform
                            float best = __fadd_rn(dd[0], col[0]);
                            int arg = 0;
#pragma unroll
                            for (int i = 1; i < 16; ++i) {
                                float s = __fadd_rn(dd[i], col[i]);
                                if (s > best) arg = i;  // first-wins tie rule
                                best = fmaxf(best, s);
                            }
                            pk |= (unsigned long long)arg << (jj * 4);
                        }
                        unsigned w[4];
#pragma unroll
                        for (int qq = 0; qq < 4; ++qq) {
                            unsigned h = (unsigned)(pk >> (16 * qq)) & 0xFFFFu;
                            w[qq] = (h & 0xFu) | ((h & 0xF0u) << 4) |
                                    ((h & 0xF00u) << 8) | ((h & 0xF000u) << 12);
                        }
                        uint4 pv = make_uint4(w[0], w[1], w[2], w[3]);
                        *(uint4*)&pbuf[q][g2][r][0] = pv;
                        *(uint4*)(psi + ((size_t)b2 * T_LEN + t2) * 16) = pv;
                    }
                }
            }
        }
    } else {
        const int l = tid - 192;
        const int g3 = l >> 4, z = l & 15;
        const int b3 = blk * 4 + g3;
        for (int p = 0; p < 66; ++p) {
            __syncthreads();
            const int c = p - 2;
            if (c >= 0) {
                const int q = c & 1;
                const int n = (c == 63) ? 63 : 64;  // psi rows in chunk
                int v = z;
                for (int r = n - 1; r >= 0; --r) v = pbuf[q][g3][r][v];
                M[((size_t)b3 * 64 + c) * 16 + z] = (unsigned char)v;
            }
        }
    }
}

// ---------------------------------------------------------------------------
// k_back: per-batch block. Load M[b] (1KB) to LDS, tid0 argmax + 64-hop
// boundary chain, then 4 rounds of chunk walks with psi staged in LDS.
__global__ __launch_bounds__(256) void k_back(const unsigned char* __restrict__ psi,
                                              const float* __restrict__ carry,
                                              const unsigned char* __restrict__ M,
                                              int* __restrict__ out) {
    __shared__ unsigned char buf[16][1024];
    __shared__ unsigned char Ml[64][16];
    __shared__ unsigned char Ebl[64];
    int b = blockIdx.x, tid = threadIdx.x;
    int grp = tid >> 4, lane = tid & 15;
    ((unsigned*)Ml)[tid] = ((const unsigned*)(M + (size_t)b * 1024))[tid];
    __syncthreads();
    if (tid == 0) {
        const float* dT = carry + b * 16;
        float best = dT[0]; int zT = 0;
#pragma unroll
        for (int i = 1; i < 16; ++i) {
            float s = dT[i];
            if (s > best) zT = i;
            best = fmaxf(best, s);
        }
        out[(size_t)b * T_LEN + (T_LEN - 1)] = zT;
        int z = zT;
        for (int c = 63; c >= 0; --c) {
            Ebl[c] = (unsigned char)z;   // state at t_hi(c)
            z = Ml[c][z];
        }
    }
    __syncthreads();
    const unsigned char* pb = psi + (size_t)b * T_LEN * 16;
    for (int r4 = 0; r4 < 4; ++r4) {
        int c = r4 * 16 + grp;
        int t_lo = c * 64;
        int t_hi = t_lo + 64; if (t_hi > T_LEN - 1) t_hi = T_LEN - 1;
        int n16 = t_hi - t_lo;
        const uint4* src = (const uint4*)(pb + (size_t)(t_lo + 1) * 16);
        uint4* dst = (uint4*)buf[grp];
        for (int qq = lane; qq < n16; qq += 16) dst[qq] = src[qq];
        __syncthreads();
        if (lane == 0) {
            int cur = Ebl[c];
            int* ob = out + (size_t)b * T_LEN;
            for (int t = t_hi; t > t_lo; --t) {
                cur = buf[grp][(t - t_lo - 1) * 16 + cur];
                ob[t - 1] = cur;
            }
        }
        __syncthreads();
    }
}

// ---------------------------------------------------------------------------
extern "C" void kernel_launch(void* const* d_in, const int* in_sizes, int n_in,
                              void* d_out, int out_size, void* d_ws, size_t ws_size,
                              hipStream_t stream) {
    (void)in_sizes; (void)n_in; (void)out_size; (void)ws_size;
    const float* x   = (const float*)d_in[0];   // [512][4096] fp32
    const float* hmm = (const float*)d_in[1];   // [64][16][16] fp32 (only [0] used)
    int* out = (int*)d_out;                     // [512][4096] int32

    char* w = (char*)d_ws;
    float* logA  = (float*)w;                                  // 1KB
    float* logAT = (float*)(w + 1024);                         // 1KB (4KB slot)
    float* carry = (float*)(w + 4096);                         // 32KB
    unsigned char* psi = (unsigned char*)(w + 4096 + 32768);   // 33.55MB
    unsigned char* M   = psi + (size_t)B_SZ * T_LEN * 16;      // 512KB
    float* Em = (float*)(M + (size_t)B_SZ * 64 * 16);          // 8.4MB (no alias)

    hipLaunchKernelGGL(k_emit, dim3((B_SZ * T_LEN / 4) / 256), dim3(256), 0, stream,
                       x, Em, hmm, logA, logAT);

    hipLaunchKernelGGL(k_main, dim3(B_SZ / 4), dim3(256), 0, stream,
                       Em, logA, logAT, psi, M, carry);

    hipLaunchKernelGGL(k_back, dim3(B_SZ), dim3(256), 0, stream,
                       psi, carry, M, out);
}

// Round 10
// 404.277 us; speedup vs baseline: 1.1131x; 1.1131x over previous
//
#include <hip/hip_runtime.h>
#include <math.h>

#define T_LEN 4096
#define B_SZ  512

// emission: fl(fl(fl(-0.5*x)*x) - fl32(0.5*log(2*pi)))
__device__ __forceinline__ float emis(float xv) {
    float a = __fmul_rn(-0.5f, xv);
    float b = __fmul_rn(a, xv);
    return __fsub_rn(b, (float)0.9189385332046727);
}

// ---------------------------------------------------------------------------
// Fused prep+emit. Block 0 computes logA (numpy pairwise-16 rowsum, fp64 log
// rounded to fp32) and logAT; all blocks compute E = emis(x).
__global__ __launch_bounds__(256) void k_emit(const float* __restrict__ x,
                                              float* __restrict__ E,
                                              const float* __restrict__ hmm,
                                              float* __restrict__ logA,
                                              float* __restrict__ logAT) {
    int tid = threadIdx.x;
    if (blockIdx.x == 0) {
        int i = tid >> 4, j = tid & 15;
        const float* row = hmm + i * 16;
        float r[8];
#pragma unroll
        for (int k = 0; k < 8; ++k) r[k] = __fadd_rn(row[k], row[k + 8]);
        float s = __fadd_rn(
            __fadd_rn(__fadd_rn(r[0], r[1]), __fadd_rn(r[2], r[3])),
            __fadd_rn(__fadd_rn(r[4], r[5]), __fadd_rn(r[6], r[7])));
        float la = (float)log((double)row[j]);
        float ls = (float)log((double)s);
        float v = __fsub_rn(la, ls);
        logA[tid] = v;
        logAT[j * 16 + i] = v;
    }
    int i = blockIdx.x * 256 + tid;
    float4 v = ((const float4*)x)[i];
    float4 e;
    e.x = emis(v.x); e.y = emis(v.y); e.z = emis(v.z); e.w = emis(v.w);
    ((float4*)E)[i] = e;
}

// ---------------------------------------------------------------------------
// Forward: 4 batches/wave, 16 lanes/batch. Hierarchical exchange as ONE asm
// block per step (hand-ordered, DPP-hazard-safe): s_nop guard; 3 mov_dpp
// row_ror:{4,8,12}; 12 v_add_f32_dpp quad_perm (rotate fused into add);
// 4 plain adds; v_max3 tree; final add. Every DPP read is >=6 instrs after
// its producer's write. Coefficients self-calibrated by applying identical
// DPP ctrls to the lane id. Adds identical, max reassoc rounding-free.
#define DPP0(CTRL, SRC) __builtin_amdgcn_update_dpp(0, (SRC), (CTRL), 0xF, 0xF, false)

#define STEPQ(ET, ROWIDX)                                                              \
    {                                                                                  \
        float s0, s1, s2, s3, s4, s5, s6, s7, s8, s9, s10, s11, s12, s13, s14, s15;    \
        asm volatile(                                                                  \
            "s_nop 1\n\t"                                                              \
            "v_mov_b32_dpp %[s4], %[dd] row_ror:4 row_mask:0xf bank_mask:0xf\n\t"      \
            "v_mov_b32_dpp %[s8], %[dd] row_ror:8 row_mask:0xf bank_mask:0xf\n\t"      \
            "v_mov_b32_dpp %[s12], %[dd] row_ror:12 row_mask:0xf bank_mask:0xf\n\t"    \
            "v_add_f32 %[s0], %[dd], %[a0]\n\t"                                        \
            "v_add_f32_dpp %[s1], %[dd], %[a1] quad_perm:[1,2,3,0] row_mask:0xf bank_mask:0xf\n\t"  \
            "v_add_f32_dpp %[s2], %[dd], %[a2] quad_perm:[2,3,0,1] row_mask:0xf bank_mask:0xf\n\t"  \
            "v_add_f32_dpp %[s3], %[dd], %[a3] quad_perm:[3,0,1,2] row_mask:0xf bank_mask:0xf\n\t"  \
            "v_add_f32_dpp %[s5], %[s4], %[a5] quad_perm:[1,2,3,0] row_mask:0xf bank_mask:0xf\n\t"  \
            "v_add_f32_dpp %[s6], %[s4], %[a6] quad_perm:[2,3,0,1] row_mask:0xf bank_mask:0xf\n\t"  \
            "v_add_f32_dpp %[s7], %[s4], %[a7] quad_perm:[3,0,1,2] row_mask:0xf bank_mask:0xf\n\t"  \
            "v_add_f32 %[s4], %[s4], %[a4]\n\t"                                        \
            "v_add_f32_dpp %[s9], %[s8], %[a9] quad_perm:[1,2,3,0] row_mask:0xf bank_mask:0xf\n\t"  \
            "v_add_f32_dpp %[s10], %[s8], %[a10] quad_perm:[2,3,0,1] row_mask:0xf bank_mask:0xf\n\t"\
            "v_add_f32_dpp %[s11], %[s8], %[a11] quad_perm:[3,0,1,2] row_mask:0xf bank_mask:0xf\n\t"\
            "v_add_f32 %[s8], %[s8], %[a8]\n\t"                                        \
            "v_add_f32_dpp %[s13], %[s12], %[a13] quad_perm:[1,2,3,0] row_mask:0xf bank_mask:0xf\n\t" \
            "v_add_f32_dpp %[s14], %[s12], %[a14] quad_perm:[2,3,0,1] row_mask:0xf bank_mask:0xf\n\t" \
            "v_add_f32_dpp %[s15], %[s12], %[a15] quad_perm:[3,0,1,2] row_mask:0xf bank_mask:0xf\n\t" \
            "v_add_f32 %[s12], %[s12], %[a12]\n\t"                                     \
            "v_max3_f32 %[s0], %[s0], %[s1], %[s2]\n\t"                                \
            "v_max3_f32 %[s3], %[s3], %[s4], %[s5]\n\t"                                \
            "v_max3_f32 %[s6], %[s6], %[s7], %[s8]\n\t"                                \
            "v_max3_f32 %[s9], %[s9], %[s10], %[s11]\n\t"                              \
            "v_max3_f32 %[s12], %[s12], %[s13], %[s14]\n\t"                            \
            "v_max3_f32 %[s0], %[s0], %[s3], %[s6]\n\t"                                \
            "v_max3_f32 %[s9], %[s9], %[s12], %[s15]\n\t"                              \
            "v_max_f32 %[s0], %[s0], %[s9]\n\t"                                        \
            "v_add_f32 %[dd], %[s0], %[et]\n\t"                                        \
            : [dd] "+v"(d),                                                            \
              [s0] "=&v"(s0), [s1] "=&v"(s1), [s2] "=&v"(s2), [s3] "=&v"(s3),          \
              [s4] "=&v"(s4), [s5] "=&v"(s5), [s6] "=&v"(s6), [s7] "=&v"(s7),          \
              [s8] "=&v"(s8), [s9] "=&v"(s9), [s10] "=&v"(s10), [s11] "=&v"(s11),      \
              [s12] "=&v"(s12), [s13] "=&v"(s13), [s14] "=&v"(s14), [s15] "=&v"(s15)   \
            : [a0] "v"(a[0]), [a1] "v"(a[1]), [a2] "v"(a[2]), [a3] "v"(a[3]),          \
              [a4] "v"(a[4]), [a5] "v"(a[5]), [a6] "v"(a[6]), [a7] "v"(a[7]),          \
              [a8] "v"(a[8]), [a9] "v"(a[9]), [a10] "v"(a[10]), [a11] "v"(a[11]),      \
              [a12] "v"(a[12]), [a13] "v"(a[13]), [a14] "v"(a[14]), [a15] "v"(a[15]),  \
              [et] "v"(ET));                                                           \
        dcol[(ROWIDX) * 16] = d;                                                       \
    }

__global__ __launch_bounds__(64) void k_fwd(const float* __restrict__ E,
                                            const float* __restrict__ logA,
                                            float* __restrict__ dchunk,
                                            float* __restrict__ carry) {
    const int lane = threadIdx.x;
    const int j = lane & 15;
    const int b = blockIdx.x * 4 + (lane >> 4);

    // Self-calibrated source-state indices: apply the exact STEPQ data
    // movement (same ctrl codes) to the lane id, then load coefficients.
    float a[16];
    {
        int s_[16];
        s_[0] = j;
        s_[1] = DPP0(0x39, j);  s_[2] = DPP0(0x4E, j);  s_[3] = DPP0(0x93, j);
        int j4 = DPP0(0x124, j);
        s_[4] = j4;
        s_[5] = DPP0(0x39, j4); s_[6] = DPP0(0x4E, j4); s_[7] = DPP0(0x93, j4);
        int j8 = DPP0(0x128, j);
        s_[8] = j8;
        s_[9] = DPP0(0x39, j8); s_[10] = DPP0(0x4E, j8); s_[11] = DPP0(0x93, j8);
        int j12 = DPP0(0x12C, j);
        s_[12] = j12;
        s_[13] = DPP0(0x39, j12); s_[14] = DPP0(0x4E, j12); s_[15] = DPP0(0x93, j12);
#pragma unroll
        for (int k = 0; k < 16; ++k) a[k] = logA[s_[k] * 16 + j];
    }

    const float* eb = E + b * T_LEN;
    float* dcol = dchunk + b * T_LEN * 16 + j;

    // t = 0: delta0 = fl(log_pi[j] + E[b][0]); log_pi == logA row 0.
    float d = __fadd_rn(logA[j], eb[0]);
    dcol[0] = d;

    int t = 1;
    for (; t < 4; ++t) { STEPQ(eb[t], t) }

    float4 q0 = *(const float4*)(eb + t);
    float4 q1 = *(const float4*)(eb + t + 4);
    float4 q2 = *(const float4*)(eb + t + 8);
    float4 q3 = *(const float4*)(eb + t + 12);
    while (t + 15 <= T_LEN - 1) {
        STEPQ(q0.x, t) STEPQ(q0.y, t + 1) STEPQ(q0.z, t + 2) STEPQ(q0.w, t + 3)
        q0 = *(const float4*)(eb + t + 16);
        STEPQ(q1.x, t + 4) STEPQ(q1.y, t + 5) STEPQ(q1.z, t + 6) STEPQ(q1.w, t + 7)
        q1 = *(const float4*)(eb + t + 20);
        STEPQ(q2.x, t + 8) STEPQ(q2.y, t + 9) STEPQ(q2.z, t + 10) STEPQ(q2.w, t + 11)
        q2 = *(const float4*)(eb + t + 24);
        STEPQ(q3.x, t + 12) STEPQ(q3.y, t + 13) STEPQ(q3.z, t + 14) STEPQ(q3.w, t + 15)
        q3 = *(const float4*)(eb + t + 28);
        t += 16;
    }
    for (; t <= T_LEN - 1; ++t) { STEPQ(eb[t], t) }
    carry[b * 16 + j] = d;
}

// ---------------------------------------------------------------------------
// psi: one thread per (b,t). AT columns via SCALAR path (wave-uniform logAT,
// jj loop not unrolled) -> zero LDS traffic. (Proven R4-R7.)
__global__ __launch_bounds__(256) void k_psi(const float* __restrict__ dchunk,
                                             const float* __restrict__ logAT,
                                             unsigned char* __restrict__ psi) {
    int tt = blockIdx.x * 256 + threadIdx.x;
    if (tt >= T_LEN - 1) return;
    int b = blockIdx.y;
    const float4* dr = (const float4*)(dchunk + ((size_t)b * T_LEN + tt) * 16);
    float4 v0 = dr[0], v1 = dr[1], v2 = dr[2], v3 = dr[3];
    float dd[16] = {v0.x, v0.y, v0.z, v0.w, v1.x, v1.y, v1.z, v1.w,
                    v2.x, v2.y, v2.z, v2.w, v3.x, v3.y, v3.z, v3.w};
    unsigned long long pk = 0ull;
#pragma clang loop unroll(disable)
    for (int jj = 0; jj < 16; ++jj) {
        const float* col = logAT + (jj << 4);
        float best = __fadd_rn(dd[0], col[0]);
        int arg = 0;
#pragma unroll
        for (int i = 1; i < 16; ++i) {
            float s = __fadd_rn(dd[i], col[i]);
            if (s > best) arg = i;  // first-wins tie rule (i ascending)
            best = fmaxf(best, s);
        }
        pk |= (unsigned long long)arg << (jj * 4);
    }
    unsigned w[4];
#pragma unroll
    for (int q = 0; q < 4; ++q) {
        unsigned h = (unsigned)(pk >> (16 * q)) & 0xFFFFu;
        w[q] = (h & 0xFu) | ((h & 0xF0u) << 4) | ((h & 0xF00u) << 8) | ((h & 0xF000u) << 12);
    }
    int t = 1 + tt;
    *((uint4*)(psi + ((size_t)b * T_LEN + t) * 16)) = make_uint4(w[0], w[1], w[2], w[3]);
}

// ---------------------------------------------------------------------------
// Fused backtrace (proven R7): one block per batch, maps/boundary in LDS.
__global__ __launch_bounds__(256) void k_back(const unsigned char* __restrict__ psi,
                                              const float* __restrict__ carry,
                                              int* __restrict__ out) {
    __shared__ unsigned char buf[16][1024];
    __shared__ unsigned char Ml[64][16];
    __shared__ unsigned char Ebl[64];
    int b = blockIdx.x, tid = threadIdx.x;
    int grp = tid >> 4, lane = tid & 15;
    const unsigned char* pb = psi + (size_t)b * T_LEN * 16;

    for (int r = 0; r < 4; ++r) {
        int c = r * 16 + grp;
        int t_lo = c * 64;
        int t_hi = t_lo + 64; if (t_hi > T_LEN - 1) t_hi = T_LEN - 1;
        int n16 = t_hi - t_lo;
        const uint4* src = (const uint4*)(pb + (size_t)(t_lo + 1) * 16);
        uint4* dst = (uint4*)buf[grp];
        for (int q = lane; q < n16; q += 16) dst[q] = src[q];
        __syncthreads();
        int v = lane;
        for (int t = t_hi; t > t_lo; --t) v = buf[grp][(t - t_lo - 1) * 16 + v];
        Ml[c][lane] = (unsigned char)v;
        __syncthreads();
    }
    if (tid == 0) {
        const float* dT = carry + b * 16;
        float best = dT[0]; int zT = 0;
#pragma unroll
        for (int i = 1; i < 16; ++i) {
            float s = dT[i];
            if (s > best) zT = i;
            best = fmaxf(best, s);
        }
        out[(size_t)b * T_LEN + (T_LEN - 1)] = zT;
        int z = zT;
        for (int c = 63; c >= 0; --c) {
            Ebl[c] = (unsigned char)z;
            z = Ml[c][z];
        }
    }
    __syncthreads();
    for (int r = 0; r < 4; ++r) {
        int c = r * 16 + grp;
        int t_lo = c * 64;
        int t_hi = t_lo + 64; if (t_hi > T_LEN - 1) t_hi = T_LEN - 1;
        int n16 = t_hi - t_lo;
        const uint4* src = (const uint4*)(pb + (size_t)(t_lo + 1) * 16);
        uint4* dst = (uint4*)buf[grp];
        for (int q = lane; q < n16; q += 16) dst[q] = src[q];
        __syncthreads();
        if (lane == 0) {
            int cur = Ebl[c];
            int* ob = out + (size_t)b * T_LEN;
            for (int t = t_hi; t > t_lo; --t) {
                cur = buf[grp][(t - t_lo - 1) * 16 + cur];
                ob[t - 1] = cur;
            }
        }
        __syncthreads();
    }
}

// ---------------------------------------------------------------------------
extern "C" void kernel_launch(void* const* d_in, const int* in_sizes, int n_in,
                              void* d_out, int out_size, void* d_ws, size_t ws_size,
                              hipStream_t stream) {
    (void)in_sizes; (void)n_in; (void)out_size; (void)ws_size;
    const float* x   = (const float*)d_in[0];   // [512][4096] fp32
    const float* hmm = (const float*)d_in[1];   // [64][16][16] fp32 (only [0] used)
    int* out = (int*)d_out;                     // [512][4096] int32

    char* w = (char*)d_ws;
    float* logA  = (float*)w;                                  // 1KB
    float* logAT = (float*)(w + 1024);                         // 1KB (4KB slot)
    float* carry = (float*)(w + 4096);                         // 32KB
    unsigned char* psi = (unsigned char*)(w + 4096 + 32768);   // 33.55MB
    float* dchunk = (float*)(psi + (size_t)B_SZ * T_LEN * 16); // 134.2MB
    float* Em = (float*)psi;  // emissions alias psi region (consumed pre-k_psi)

    hipLaunchKernelGGL(k_emit, dim3((B_SZ * T_LEN / 4) / 256), dim3(256), 0, stream,
                       x, Em, hmm, logA, logAT);

    hipLaunchKernelGGL(k_fwd, dim3(B_SZ / 4), dim3(64), 0, stream,
                       Em, logA, dchunk, carry);

    hipLaunchKernelGGL(k_psi, dim3((T_LEN - 1 + 255) / 256, B_SZ), dim3(256), 0, stream,
                       dchunk, logAT, psi);

    hipLaunchKernelGGL(k_back, dim3(B_SZ), dim3(256), 0, stream,
                       psi, carry, out);
}

// Round 11
// 366.758 us; speedup vs baseline: 1.2270x; 1.1023x over previous
//
#include <hip/hip_runtime.h>
#include <math.h>

#define T_LEN 4096
#define B_SZ  512

// emission: fl(fl(fl(-0.5*x)*x) - fl32(0.5*log(2*pi)))
__device__ __forceinline__ float emis(float xv) {
    float a = __fmul_rn(-0.5f, xv);
    float b = __fmul_rn(a, xv);
    return __fsub_rn(b, (float)0.9189385332046727);
}

// ---------------------------------------------------------------------------
// Fused prep+emit (proven). Block 0 computes logA (numpy pairwise-16 rowsum,
// fp64 log rounded to fp32) and logAT; all blocks compute E = emis(x).
__global__ __launch_bounds__(256) void k_emit(const float* __restrict__ x,
                                              float* __restrict__ E,
                                              const float* __restrict__ hmm,
                                              float* __restrict__ logA,
                                              float* __restrict__ logAT) {
    int tid = threadIdx.x;
    if (blockIdx.x == 0) {
        int i = tid >> 4, j = tid & 15;
        const float* row = hmm + i * 16;
        float r[8];
#pragma unroll
        for (int k = 0; k < 8; ++k) r[k] = __fadd_rn(row[k], row[k + 8]);
        float s = __fadd_rn(
            __fadd_rn(__fadd_rn(r[0], r[1]), __fadd_rn(r[2], r[3])),
            __fadd_rn(__fadd_rn(r[4], r[5]), __fadd_rn(r[6], r[7])));
        float la = (float)log((double)row[j]);
        float ls = (float)log((double)s);
        float v = __fsub_rn(la, ls);
        logA[tid] = v;
        logAT[j * 16 + i] = v;
    }
    int i = blockIdx.x * 256 + tid;
    float4 v = ((const float4*)x)[i];
    float4 e;
    e.x = emis(v.x); e.y = emis(v.y); e.z = emis(v.z); e.w = emis(v.w);
    ((float4*)E)[i] = e;
}

// ---------------------------------------------------------------------------
// Forward (R3 champion, 136.6 cyc/step — structural floor: 31 slots x 2cyc +
// 15 DPP x 5cyc surcharge): 4 batches/wave, v_add_f32_dpp row_ror fused adds.
#define DPP_ROR0(K, SRC) __builtin_amdgcn_update_dpp(0, (SRC), 0x120 + (K), 0xF, 0xF, false)
#define M3(x, y, z) fmaxf(fmaxf(x, y), z)

#define ADDPP(DST, K)                                                                 \
    asm("v_add_f32_dpp %0, %1, %2 row_ror:" #K " row_mask:0xf bank_mask:0xf"          \
        : "=v"(DST) : "v"(d), "v"(a[K]))

#define STEPA(ET, ROWIDX)                                                             \
    {                                                                                 \
        float s0 = __fadd_rn(d, a[0]);                                                \
        float s1, s2, s3, s4, s5, s6, s7, s8, s9, s10, s11, s12, s13, s14, s15;       \
        ADDPP(s1, 1);   ADDPP(s2, 2);   ADDPP(s3, 3);   ADDPP(s4, 4);                 \
        ADDPP(s5, 5);   ADDPP(s6, 6);   ADDPP(s7, 7);   ADDPP(s8, 8);                 \
        ADDPP(s9, 9);   ADDPP(s10, 10); ADDPP(s11, 11); ADDPP(s12, 12);               \
        ADDPP(s13, 13); ADDPP(s14, 14); ADDPP(s15, 15);                               \
        float u0 = M3(s0, s1, s2),  u1 = M3(s3, s4, s5),  u2 = M3(s6, s7, s8);        \
        float u3 = M3(s9, s10, s11), u4 = M3(s12, s13, s14);                          \
        float m = fmaxf(M3(u0, u1, u2), M3(u3, u4, s15));                             \
        d = __fadd_rn(m, ET);                                                         \
        dcol[(ROWIDX) * 16] = d;                                                      \
    }

__global__ __launch_bounds__(64) void k_fwd(const float* __restrict__ E,
                                            const float* __restrict__ logA,
                                            float* __restrict__ dchunk,
                                            float* __restrict__ carry) {
    const int lane = threadIdx.x;
    const int j = lane & 15;
    const int b = blockIdx.x * 4 + (lane >> 4);
    float a[16];
    a[0] = logA[j * 16 + j];
#define LOADA(K) { int sk = DPP_ROR0(K, j); a[K] = logA[sk * 16 + j]; }
    LOADA(1)  LOADA(2)  LOADA(3)  LOADA(4)  LOADA(5)
    LOADA(6)  LOADA(7)  LOADA(8)  LOADA(9)  LOADA(10)
    LOADA(11) LOADA(12) LOADA(13) LOADA(14) LOADA(15)
#undef LOADA
    const float* eb = E + b * T_LEN;
    float* dcol = dchunk + b * T_LEN * 16 + j;

    float d = __fadd_rn(logA[j], eb[0]);
    dcol[0] = d;

    int t = 1;
    for (; t < 4; ++t) { STEPA(eb[t], t) }

    float4 q0 = *(const float4*)(eb + t);
    float4 q1 = *(const float4*)(eb + t + 4);
    float4 q2 = *(const float4*)(eb + t + 8);
    float4 q3 = *(const float4*)(eb + t + 12);
    while (t + 15 <= T_LEN - 1) {
        STEPA(q0.x, t) STEPA(q0.y, t + 1) STEPA(q0.z, t + 2) STEPA(q0.w, t + 3)
        q0 = *(const float4*)(eb + t + 16);
        STEPA(q1.x, t + 4) STEPA(q1.y, t + 5) STEPA(q1.z, t + 6) STEPA(q1.w, t + 7)
        q1 = *(const float4*)(eb + t + 20);
        STEPA(q2.x, t + 8) STEPA(q2.y, t + 9) STEPA(q2.z, t + 10) STEPA(q2.w, t + 11)
        q2 = *(const float4*)(eb + t + 24);
        STEPA(q3.x, t + 12) STEPA(q3.y, t + 13) STEPA(q3.z, t + 14) STEPA(q3.w, t + 15)
        q3 = *(const float4*)(eb + t + 28);
        t += 16;
    }
    for (; t <= T_LEN - 1; ++t) { STEPA(eb[t], t) }
    carry[b * 16 + j] = d;
}

// ---------------------------------------------------------------------------
// psi (proven): one thread per (b,t), scalar-path logAT, first-wins argmax.
__global__ __launch_bounds__(256) void k_psi(const float* __restrict__ dchunk,
                                             const float* __restrict__ logAT,
                                             unsigned char* __restrict__ psi) {
    int tt = blockIdx.x * 256 + threadIdx.x;
    if (tt >= T_LEN - 1) return;
    int b = blockIdx.y;
    const float4* dr = (const float4*)(dchunk + ((size_t)b * T_LEN + tt) * 16);
    float4 v0 = dr[0], v1 = dr[1], v2 = dr[2], v3 = dr[3];
    float dd[16] = {v0.x, v0.y, v0.z, v0.w, v1.x, v1.y, v1.z, v1.w,
                    v2.x, v2.y, v2.z, v2.w, v3.x, v3.y, v3.z, v3.w};
    unsigned long long pk = 0ull;
#pragma clang loop unroll(disable)
    for (int jj = 0; jj < 16; ++jj) {
        const float* col = logAT + (jj << 4);
        float best = __fadd_rn(dd[0], col[0]);
        int arg = 0;
#pragma unroll
        for (int i = 1; i < 16; ++i) {
            float s = __fadd_rn(dd[i], col[i]);
            if (s > best) arg = i;  // first-wins tie rule (i ascending)
            best = fmaxf(best, s);
        }
        pk |= (unsigned long long)arg << (jj * 4);
    }
    unsigned w[4];
#pragma unroll
    for (int q = 0; q < 4; ++q) {
        unsigned h = (unsigned)(pk >> (16 * q)) & 0xFFFFu;
        w[q] = (h & 0xFu) | ((h & 0xF0u) << 4) | ((h & 0xF00u) << 8) | ((h & 0xF000u) << 12);
    }
    int t = 1 + tt;
    *((uint4*)(psi + ((size_t)b * T_LEN + t) * 16)) = make_uint4(w[0], w[1], w[2], w[3]);
}

// ---------------------------------------------------------------------------
// Backtrace with register map-application: psi rows prefetched 8-deep from
// LDS into VGPRs (ds_read_b128, addresses independent of chain state), map
// applied via v_perm_b32 byte-select (~6 VALU/hop vs ~120cyc dependent LDS).
// v_perm_b32 D,S0,S1,S2: sel 0-3 -> S1 bytes, 4-7 -> S0 bytes.
#define PERMSEL(V, Q)                                                                 \
    {                                                                                 \
        int sel_ = (V) & 7;                                                           \
        int lo_, hi_;                                                                 \
        asm("v_perm_b32 %0, %1, %2, %3" : "=v"(lo_) : "v"((Q).y), "v"((Q).x), "v"(sel_)); \
        asm("v_perm_b32 %0, %1, %2, %3" : "=v"(hi_) : "v"((Q).w), "v"((Q).z), "v"(sel_)); \
        V = (((V) & 8) ? hi_ : lo_) & 0xff;                                           \
    }

// 64 hops over rows 63..0 at BASE (16B rows), 8-deep prefetch.
// PRE(r,cur) runs before the hop of row r, POST(r,cur) after.
#define WALK64(BASE, CUR, PRE, POST)                                                  \
    {                                                                                 \
        uint4 m_[8];                                                                  \
        _Pragma("unroll") for (int z_ = 0; z_ < 8; ++z_)                              \
            m_[z_] = *(const uint4*)((BASE) + (63 - z_) * 16);                        \
        for (int r_ = 63; r_ >= 15; r_ -= 8) {                                        \
            uint4 n_[8];                                                              \
            _Pragma("unroll") for (int z_ = 0; z_ < 8; ++z_)                          \
                n_[z_] = *(const uint4*)((BASE) + (r_ - 8 - z_) * 16);                \
            _Pragma("unroll") for (int z_ = 0; z_ < 8; ++z_) {                        \
                PRE(r_ - z_, CUR) PERMSEL(CUR, m_[z_]) POST(r_ - z_, CUR)             \
            }                                                                         \
            _Pragma("unroll") for (int z_ = 0; z_ < 8; ++z_) m_[z_] = n_[z_];         \
        }                                                                             \
        _Pragma("unroll") for (int z_ = 0; z_ < 8; ++z_) {                            \
            PRE(7 - z_, CUR) PERMSEL(CUR, m_[z_]) POST(7 - z_, CUR)                   \
        }                                                                             \
    }

#define NOPX(r, c)
#define EBL_PRE(r, c) Ebl[r] = (unsigned char)(c);
#define OUT_POST(r, c) ob[r] = (c);

__global__ __launch_bounds__(256) void k_back(const unsigned char* __restrict__ psi,
                                              const float* __restrict__ carry,
                                              int* __restrict__ out) {
    __shared__ uint4 bufv[64 * 65];          // 64 chunks x 1040B (pad kills bank alias)
    __shared__ uint4 Mlv[64];                // chunk maps, 16B rows
    __shared__ unsigned char Ebl[64];
    unsigned char* bufb = (unsigned char*)bufv;
    unsigned char* Ml = (unsigned char*)Mlv;
    const int b = blockIdx.x, tid = threadIdx.x;
    const int grp = tid >> 4, lane = tid & 15;

    // Stage psi[b][1..4095] into chunked LDS: chunk c row r = psi[t=64c+1+r].
    const uint4* src = (const uint4*)(psi + (size_t)b * T_LEN * 16 + 16);
    for (int k = tid; k < T_LEN - 1; k += 256) {
        *(uint4*)(bufb + (k >> 6) * 1040 + (k & 63) * 16) = src[k];
    }
    if (tid == 255)  // identity-pad chunk 63 row 63 (t=4096 doesn't exist)
        *(uint4*)(bufb + 63 * 1040 + 63 * 16) =
            make_uint4(0x03020100u, 0x07060504u, 0x0B0A0908u, 0x0F0E0D0Cu);
    __syncthreads();

    // Phase A: 64 chunk maps (16 groups x 4 rounds, 16 states/chunk).
    for (int q = 0; q < 4; ++q) {
        int c = q * 16 + grp;
        const unsigned char* baseA = bufb + c * 1040;
        int cur = lane;
        WALK64(baseA, cur, NOPX, NOPX)
        Ml[c * 16 + lane] = (unsigned char)cur;
    }
    __syncthreads();

    // Boundary: argmax(deltaT) (first-wins) + 64-hop chain over chunk maps.
    if (tid == 0) {
        const float* dT = carry + b * 16;
        float best = dT[0]; int zT = 0;
#pragma unroll
        for (int i = 1; i < 16; ++i) {
            float s = dT[i];
            if (s > best) zT = i;
            best = fmaxf(best, s);
        }
        int z = zT;
        WALK64(Ml, z, EBL_PRE, NOPX)
    }
    __syncthreads();

    // Phase C: one lane per chunk walks and writes the path (chunk 63's
    // identity row harmlessly rewrites out[4095] = zT).
    if (tid < 64) {
        const unsigned char* baseC = bufb + tid * 1040;
        int* ob = out + (size_t)b * T_LEN + tid * 64;
        int cur = Ebl[tid];
        WALK64(baseC, cur, NOPX, OUT_POST)
    }
}

// ---------------------------------------------------------------------------
extern "C" void kernel_launch(void* const* d_in, const int* in_sizes, int n_in,
                              void* d_out, int out_size, void* d_ws, size_t ws_size,
                              hipStream_t stream) {
    (void)in_sizes; (void)n_in; (void)out_size; (void)ws_size;
    const float* x   = (const float*)d_in[0];   // [512][4096] fp32
    const float* hmm = (const float*)d_in[1];   // [64][16][16] fp32 (only [0] used)
    int* out = (int*)d_out;                     // [512][4096] int32

    char* w = (char*)d_ws;
    float* logA  = (float*)w;                                  // 1KB
    float* logAT = (float*)(w + 1024);                         // 1KB (4KB slot)
    float* carry = (float*)(w + 4096);                         // 32KB
    unsigned char* psi = (unsigned char*)(w + 4096 + 32768);   // 33.55MB
    float* dchunk = (float*)(psi + (size_t)B_SZ * T_LEN * 16); // 134.2MB
    float* Em = (float*)psi;  // emissions alias psi region (consumed pre-k_psi)

    hipLaunchKernelGGL(k_emit, dim3((B_SZ * T_LEN / 4) / 256), dim3(256), 0, stream,
                       x, Em, hmm, logA, logAT);

    hipLaunchKernelGGL(k_fwd, dim3(B_SZ / 4), dim3(64), 0, stream,
                       Em, logA, dchunk, carry);

    hipLaunchKernelGGL(k_psi, dim3((T_LEN - 1 + 255) / 256, B_SZ), dim3(256), 0, stream,
                       dchunk, logAT, psi);

    hipLaunchKernelGGL(k_back, dim3(B_SZ), dim3(256), 0, stream,
                       psi, carry, out);
}

// Round 12
// 312.797 us; speedup vs baseline: 1.4387x; 1.1725x over previous
//
#include <hip/hip_runtime.h>
#include <math.h>

#define T_LEN 4096
#define B_SZ  512

// emission: fl(fl(fl(-0.5*x)*x) - fl32(0.5*log(2*pi)))
__device__ __forceinline__ float emis(float xv) {
    float a = __fmul_rn(-0.5f, xv);
    float b = __fmul_rn(a, xv);
    return __fsub_rn(b, (float)0.9189385332046727);
}

// ---------------------------------------------------------------------------
// k_emit: block 0 computes logA/logAT (numpy pairwise-16 rowsum, fp64 log);
// all blocks: Epad[b][u] = emis(x[b][u+1]) (shifted so phase loads are
// 16B-aligned), E0[b] = emis(x[b][0]).
__global__ __launch_bounds__(256) void k_emit(const float* __restrict__ x,
                                              float* __restrict__ Epad,
                                              float* __restrict__ E0,
                                              const float* __restrict__ hmm,
                                              float* __restrict__ logA,
                                              float* __restrict__ logAT) {
    int tid = threadIdx.x;
    if (blockIdx.x == 0) {
        int i = tid >> 4, j = tid & 15;
        const float* row = hmm + i * 16;
        float r[8];
#pragma unroll
        for (int k = 0; k < 8; ++k) r[k] = __fadd_rn(row[k], row[k + 8]);
        float s = __fadd_rn(
            __fadd_rn(__fadd_rn(r[0], r[1]), __fadd_rn(r[2], r[3])),
            __fadd_rn(__fadd_rn(r[4], r[5]), __fadd_rn(r[6], r[7])));
        float la = (float)log((double)row[j]);
        float ls = (float)log((double)s);
        float v = __fsub_rn(la, ls);
        logA[tid] = v;
        logAT[j * 16 + i] = v;
    }
    int i = blockIdx.x * 256 + tid;
    const float4* x4 = (const float4*)x;
    float4 xa = x4[i];
    float4 xb = (i + 1 < (B_SZ * T_LEN / 4)) ? x4[i + 1] : xa;
    float4 e;
    e.x = emis(xa.y); e.y = emis(xa.z); e.z = emis(xa.w); e.w = emis(xb.x);
    ((float4*)Epad)[i] = e;
    if ((i & 1023) == 0) E0[i >> 10] = emis(xa.x);
}

// ---------------------------------------------------------------------------
#define DPP_ROR0(K, SRC) __builtin_amdgcn_update_dpp(0, (SRC), 0x120 + (K), 0xF, 0xF, false)
#define M3(x, y, z) fmaxf(fmaxf(x, y), z)

#define ADDPP(DST, K)                                                                 \
    asm("v_add_f32_dpp %0, %1, %2 row_ror:" #K " row_mask:0xf bank_mask:0xf"          \
        : "=v"(DST) : "v"(d), "v"(a[K]))

#define STEPC(ET)                                                                     \
    {                                                                                 \
        float s0 = __fadd_rn(d, a[0]);                                                \
        float s1, s2, s3, s4, s5, s6, s7, s8, s9, s10, s11, s12, s13, s14, s15;       \
        ADDPP(s1, 1);   ADDPP(s2, 2);   ADDPP(s3, 3);   ADDPP(s4, 4);                 \
        ADDPP(s5, 5);   ADDPP(s6, 6);   ADDPP(s7, 7);   ADDPP(s8, 8);                 \
        ADDPP(s9, 9);   ADDPP(s10, 10); ADDPP(s11, 11); ADDPP(s12, 12);               \
        ADDPP(s13, 13); ADDPP(s14, 14); ADDPP(s15, 15);                               \
        float u0 = M3(s0, s1, s2),  u1 = M3(s3, s4, s5),  u2 = M3(s6, s7, s8);        \
        float u3 = M3(s9, s10, s11), u4 = M3(s12, s13, s14);                          \
        float m = fmaxf(M3(u0, u1, u2), M3(u3, u4, s15));                             \
        d = __fadd_rn(m, ET);                                                         \
    }

#define GRP4(QV, SLOTDW)                                                              \
    {                                                                                 \
        float4 dq;                                                                    \
        STEPC(QV.x) dq.x = d; STEPC(QV.y) dq.y = d;                                   \
        STEPC(QV.z) dq.z = d; STEPC(QV.w) dq.w = d;                                   \
        *(float4*)(db + (SLOTDW)) = dq;                                               \
    }

// v_perm_b32 byte-select map application (R11-proven).
#define PERMSEL(V, Q)                                                                 \
    {                                                                                 \
        int sel_ = (V) & 7;                                                           \
        int lo_, hi_;                                                                 \
        asm("v_perm_b32 %0, %1, %2, %3" : "=v"(lo_) : "v"((Q).y), "v"((Q).x), "v"(sel_)); \
        asm("v_perm_b32 %0, %1, %2, %3" : "=v"(hi_) : "v"((Q).w), "v"((Q).z), "v"(sel_)); \
        V = (((V) & 8) ? hi_ : lo_) & 0xff;                                           \
    }

#define WALK64(BASE, CUR, PRE, POST)                                                  \
    {                                                                                 \
        uint4 m_[8];                                                                  \
        _Pragma("unroll") for (int z_ = 0; z_ < 8; ++z_)                              \
            m_[z_] = *(const uint4*)((BASE) + (63 - z_) * 16);                        \
        for (int r_ = 63; r_ >= 15; r_ -= 8) {                                        \
            uint4 n_[8];                                                              \
            _Pragma("unroll") for (int z_ = 0; z_ < 8; ++z_)                          \
                n_[z_] = *(const uint4*)((BASE) + (r_ - 8 - z_) * 16);                \
            _Pragma("unroll") for (int z_ = 0; z_ < 8; ++z_) {                        \
                PRE(r_ - z_, CUR) PERMSEL(CUR, m_[z_]) POST(r_ - z_, CUR)             \
            }                                                                         \
            _Pragma("unroll") for (int z_ = 0; z_ < 8; ++z_) m_[z_] = n_[z_];         \
        }                                                                             \
        _Pragma("unroll") for (int z_ = 0; z_ < 8; ++z_) {                            \
            PRE(7 - z_, CUR) PERMSEL(CUR, m_[z_]) POST(7 - z_, CUR)                   \
        }                                                                             \
    }

#define NOPX(r, c)
#define EBL_PRE(r, c) Ebl[r] = (unsigned char)(c);
#define OUT_POST(r, c) ob[r] = (c);

// ---------------------------------------------------------------------------
// k_main: fwd + psi + chunk maps pipelined per block. 2 batches/block.
// Wave 0 (lanes g<2): Viterbi chains, deltas -> LDS double buffer dbuf.
//   dbuf row r in 0..63 = delta at t=64p+1+r; row 64 = delta at 64p.
// Waves 1,2: psi of chunk p-1 (wave w handles batch w-1), -> pbuf + global.
// Wave 3 (lanes<32): v_perm register map-walk of chunk p-2 -> global M.
__global__ __launch_bounds__(256) void k_main(const float* __restrict__ Epad,
                                              const float* __restrict__ E0,
                                              const float* __restrict__ logA,
                                              const float* __restrict__ logAT,
                                              unsigned char* __restrict__ psi,
                                              unsigned char* __restrict__ M,
                                              float* __restrict__ carry) {
    __shared__ __align__(16) float dbuf[2][2][16][68];  // 17408 B
    __shared__ uint4 pbufv[2][2][65];                   // 4160 B (65 = bank-spread pad)
    const int tid = threadIdx.x;
    const int wave = tid >> 6;
    const int blk = blockIdx.x;

    if (wave == 0) {
        asm volatile("s_setprio 3");
        const int j = tid & 15, g = tid >> 4;  // g in 0..3; active g<2
        float a[16];
        float d = 0.f;
        float4 q0, q1, q2, q3;
        const float4* ep4 = nullptr;
        int b = 0;
        if (g < 2) {
            b = blk * 2 + g;
            a[0] = logA[j * 16 + j];
#define LOADA(K) { int sk = DPP_ROR0(K, j); a[K] = logA[sk * 16 + j]; }
            LOADA(1)  LOADA(2)  LOADA(3)  LOADA(4)  LOADA(5)
            LOADA(6)  LOADA(7)  LOADA(8)  LOADA(9)  LOADA(10)
            LOADA(11) LOADA(12) LOADA(13) LOADA(14) LOADA(15)
#undef LOADA
            ep4 = (const float4*)(Epad + (size_t)b * T_LEN);
            d = __fadd_rn(logA[j], E0[b]);   // delta0
            q0 = ep4[0]; q1 = ep4[1]; q2 = ep4[2]; q3 = ep4[3];
        }
        for (int p = 0; p < 66; ++p) {
            __syncthreads();
            if (p < 64 && g < 2) {
                float* db = &dbuf[p & 1][g][j][0];
                db[64] = d;                   // delta at t = 64p
                const float4* epc = ep4 + 16 * p;
                if (p < 63) {
#pragma clang loop unroll(disable)
                    for (int ii = 0; ii < 4; ++ii) {
                        GRP4(q0, ii * 16 + 0)  q0 = epc[(ii + 1) * 4 + 0];
                        GRP4(q1, ii * 16 + 4)  q1 = epc[(ii + 1) * 4 + 1];
                        GRP4(q2, ii * 16 + 8)  q2 = epc[(ii + 1) * 4 + 2];
                        GRP4(q3, ii * 16 + 12) q3 = epc[(ii + 1) * 4 + 3];
                    }
                } else {
#pragma clang loop unroll(disable)
                    for (int ii = 0; ii < 3; ++ii) {
                        GRP4(q0, ii * 16 + 0)  q0 = epc[(ii + 1) * 4 + 0];
                        GRP4(q1, ii * 16 + 4)  q1 = epc[(ii + 1) * 4 + 1];
                        GRP4(q2, ii * 16 + 8)  q2 = epc[(ii + 1) * 4 + 2];
                        GRP4(q3, ii * 16 + 12) q3 = epc[(ii + 1) * 4 + 3];
                    }
                    GRP4(q0, 48) GRP4(q1, 52) GRP4(q2, 56)     // t=4081..4092
                    STEPC(q3.x) db[60] = d;                     // t=4093
                    STEPC(q3.y) db[61] = d;                     // t=4094
                    STEPC(q3.z) db[62] = d;                     // t=4095
                }
            }
        }
        if (g < 2) carry[b * 16 + j] = d;
    } else if (wave <= 2) {
        const int g2 = wave - 1;       // batch within block
        const int r = tid & 63;
        const int b2 = blk * 2 + g2;
        for (int p = 0; p < 66; ++p) {
            __syncthreads();
            const int c = p - 1;
            if (c >= 0 && c < 64) {
                const int t2 = 64 * c + 1 + r;
                if (t2 <= T_LEN - 1) {
                    const int q = c & 1;
                    const int rs = (r == 0) ? 64 : (r - 1);
                    float dd[16];
#pragma unroll
                    for (int i = 0; i < 16; ++i) dd[i] = dbuf[q][g2][i][rs];
                    unsigned long long pk = 0ull;
#pragma clang loop unroll(disable)
                    for (int jj = 0; jj < 16; ++jj) {
                        const float* col = logAT + (jj << 4);   // wave-uniform
                        float best = __fadd_rn(dd[0], col[0]);
                        int arg = 0;
#pragma unroll
                        for (int i = 1; i < 16; ++i) {
                            float s = __fadd_rn(dd[i], col[i]);
                            if (s > best) arg = i;  // first-wins tie rule
                            best = fmaxf(best, s);
                        }
                        pk |= (unsigned long long)arg << (jj * 4);
                    }
                    unsigned w[4];
#pragma unroll
                    for (int qq = 0; qq < 4; ++qq) {
                        unsigned h = (unsigned)(pk >> (16 * qq)) & 0xFFFFu;
                        w[qq] = (h & 0xFu) | ((h & 0xF0u) << 4) |
                                ((h & 0xF00u) << 8) | ((h & 0xF000u) << 12);
                    }
                    uint4 pv = make_uint4(w[0], w[1], w[2], w[3]);
                    pbufv[q][g2][r] = pv;
                    *(uint4*)(psi + ((size_t)b2 * T_LEN + t2) * 16) = pv;
                }
            }
        }
    } else {
        const int l = tid - 192;
        const int g3 = l >> 4, z = l & 15;
        for (int p = 0; p < 66; ++p) {
            __syncthreads();
            const int c = p - 2;
            if (c >= 0 && l < 32) {
                const int cq = c & 1;
                if (c == 63)  // row 63 of last chunk never written: identity
                    ((unsigned char*)&pbufv[cq][g3][63])[z] = (unsigned char)z;
                asm volatile("" ::: "memory");
                const unsigned char* base = (const unsigned char*)&pbufv[cq][g3][0];
                int cur = z;
                WALK64(base, cur, NOPX, NOPX)
                M[((size_t)(blk * 2 + g3) * 64 + c) * 16 + z] = (unsigned char)cur;
            }
        }
    }
}

// ---------------------------------------------------------------------------
// k_back-lite: per-batch block. Stage psi to LDS, load M[b] (1KB), tid0
// argmax + register boundary walk, 64 lanes walk chunks writing the path.
__global__ __launch_bounds__(256) void k_back(const unsigned char* __restrict__ psi,
                                              const float* __restrict__ carry,
                                              const unsigned char* __restrict__ M,
                                              int* __restrict__ out) {
    __shared__ uint4 bufv[64 * 65];          // 64 chunks x 1040B
    __shared__ uint4 Mlv[64];
    __shared__ unsigned char Ebl[64];
    unsigned char* bufb = (unsigned char*)bufv;
    unsigned char* Ml = (unsigned char*)Mlv;
    const int b = blockIdx.x, tid = threadIdx.x;

    const uint4* src = (const uint4*)(psi + (size_t)b * T_LEN * 16 + 16);
    for (int k = tid; k < T_LEN - 1; k += 256)
        *(uint4*)(bufb + (k >> 6) * 1040 + (k & 63) * 16) = src[k];
    if (tid == 255)
        *(uint4*)(bufb + 63 * 1040 + 63 * 16) =
            make_uint4(0x03020100u, 0x07060504u, 0x0B0A0908u, 0x0F0E0D0Cu);
    if (tid < 64) Mlv[tid] = ((const uint4*)(M + (size_t)b * 1024))[tid];
    __syncthreads();

    if (tid == 0) {
        const float* dT = carry + b * 16;
        float best = dT[0]; int zT = 0;
#pragma unroll
        for (int i = 1; i < 16; ++i) {
            float s = dT[i];
            if (s > best) zT = i;
            best = fmaxf(best, s);
        }
        int z = zT;
        WALK64(Ml, z, EBL_PRE, NOPX)
    }
    __syncthreads();

    if (tid < 64) {
        const unsigned char* base = bufb + tid * 1040;
        int* ob = out + (size_t)b * T_LEN + tid * 64;
        int cur = Ebl[tid];
        WALK64(base, cur, NOPX, OUT_POST)   // chunk63 identity row rewrites out[4095]=zT
    }
}

// ---------------------------------------------------------------------------
extern "C" void kernel_launch(void* const* d_in, const int* in_sizes, int n_in,
                              void* d_out, int out_size, void* d_ws, size_t ws_size,
                              hipStream_t stream) {
    (void)in_sizes; (void)n_in; (void)out_size; (void)ws_size;
    const float* x   = (const float*)d_in[0];   // [512][4096] fp32
    const float* hmm = (const float*)d_in[1];   // [64][16][16] fp32 (only [0] used)
    int* out = (int*)d_out;                     // [512][4096] int32

    char* w = (char*)d_ws;
    float* logA  = (float*)w;                                  // 1KB
    float* logAT = (float*)(w + 1024);                         // 1KB
    float* E0    = (float*)(w + 2048);                         // 2KB
    float* carry = (float*)(w + 4096);                         // 32KB
    unsigned char* psi = (unsigned char*)(w + 4096 + 32768);   // 33.55MB
    unsigned char* M   = psi + (size_t)B_SZ * T_LEN * 16;      // 512KB
    float* Epad = (float*)(M + (size_t)B_SZ * 64 * 16);        // 8.4MB

    hipLaunchKernelGGL(k_emit, dim3((B_SZ * T_LEN / 4) / 256), dim3(256), 0, stream,
                       x, Epad, E0, hmm, logA, logAT);

    hipLaunchKernelGGL(k_main, dim3(B_SZ / 2), dim3(256), 0, stream,
                       Epad, E0, logA, logAT, psi, M, carry);

    hipLaunchKernelGGL(k_back, dim3(B_SZ), dim3(256), 0, stream,
                       psi, carry, M, out);
}

// Round 13
// 306.261 us; speedup vs baseline: 1.4694x; 1.0213x over previous
//
#include <hip/hip_runtime.h>
#include <math.h>

#define T_LEN 4096
#define B_SZ  512

// emission: fl(fl(fl(-0.5*x)*x) - fl32(0.5*log(2*pi)))
__device__ __forceinline__ float emis(float xv) {
    float a = __fmul_rn(-0.5f, xv);
    float b = __fmul_rn(a, xv);
    return __fsub_rn(b, (float)0.9189385332046727);
}

// ---------------------------------------------------------------------------
// k_emit: block 0 computes logA/logAT (numpy pairwise-16 rowsum, fp64 log);
// all blocks: Epad[b][u] = emis(x[b][u+1]), E0[b] = emis(x[b][0]).
__global__ __launch_bounds__(256) void k_emit(const float* __restrict__ x,
                                              float* __restrict__ Epad,
                                              float* __restrict__ E0,
                                              const float* __restrict__ hmm,
                                              float* __restrict__ logA,
                                              float* __restrict__ logAT) {
    int tid = threadIdx.x;
    if (blockIdx.x == 0) {
        int i = tid >> 4, j = tid & 15;
        const float* row = hmm + i * 16;
        float r[8];
#pragma unroll
        for (int k = 0; k < 8; ++k) r[k] = __fadd_rn(row[k], row[k + 8]);
        float s = __fadd_rn(
            __fadd_rn(__fadd_rn(r[0], r[1]), __fadd_rn(r[2], r[3])),
            __fadd_rn(__fadd_rn(r[4], r[5]), __fadd_rn(r[6], r[7])));
        float la = (float)log((double)row[j]);
        float ls = (float)log((double)s);
        float v = __fsub_rn(la, ls);
        logA[tid] = v;
        logAT[j * 16 + i] = v;
    }
    int i = blockIdx.x * 256 + tid;
    const float4* x4 = (const float4*)x;
    float4 xa = x4[i];
    float4 xb = (i + 1 < (B_SZ * T_LEN / 4)) ? x4[i + 1] : xa;
    float4 e;
    e.x = emis(xa.y); e.y = emis(xa.z); e.z = emis(xa.w); e.w = emis(xb.x);
    ((float4*)Epad)[i] = e;
    if ((i & 1023) == 0) E0[i >> 10] = emis(xa.x);
}

// ---------------------------------------------------------------------------
#define DPP_ROR0(K, SRC) __builtin_amdgcn_update_dpp(0, (SRC), 0x120 + (K), 0xF, 0xF, false)
#define M3(x, y, z) fmaxf(fmaxf(x, y), z)

#define ADDPP(DST, K)                                                                 \
    asm("v_add_f32_dpp %0, %1, %2 row_ror:" #K " row_mask:0xf bank_mask:0xf"          \
        : "=v"(DST) : "v"(d), "v"(a[K]))

#define STEPC(ET)                                                                     \
    {                                                                                 \
        float s0 = __fadd_rn(d, a[0]);                                                \
        float s1, s2, s3, s4, s5, s6, s7, s8, s9, s10, s11, s12, s13, s14, s15;       \
        ADDPP(s1, 1);   ADDPP(s2, 2);   ADDPP(s3, 3);   ADDPP(s4, 4);                 \
        ADDPP(s5, 5);   ADDPP(s6, 6);   ADDPP(s7, 7);   ADDPP(s8, 8);                 \
        ADDPP(s9, 9);   ADDPP(s10, 10); ADDPP(s11, 11); ADDPP(s12, 12);               \
        ADDPP(s13, 13); ADDPP(s14, 14); ADDPP(s15, 15);                               \
        float u0 = M3(s0, s1, s2),  u1 = M3(s3, s4, s5),  u2 = M3(s6, s7, s8);        \
        float u3 = M3(s9, s10, s11), u4 = M3(s12, s13, s14);                          \
        float m = fmaxf(M3(u0, u1, u2), M3(u3, u4, s15));                             \
        d = __fadd_rn(m, ET);                                                         \
    }

#define GRP4(QV, SLOTDW)                                                              \
    {                                                                                 \
        float4 dq;                                                                    \
        STEPC(QV.x) dq.x = d; STEPC(QV.y) dq.y = d;                                   \
        STEPC(QV.z) dq.z = d; STEPC(QV.w) dq.w = d;                                   \
        *(float4*)(db + (SLOTDW)) = dq;                                               \
    }

// Byte map application via v_perm (R11/R12-proven) — used for boundary chain.
#define PERMSEL(V, Q)                                                                 \
    {                                                                                 \
        int sel_ = (V) & 7;                                                           \
        int lo_, hi_;                                                                 \
        asm("v_perm_b32 %0, %1, %2, %3" : "=v"(lo_) : "v"((Q).y), "v"((Q).x), "v"(sel_)); \
        asm("v_perm_b32 %0, %1, %2, %3" : "=v"(hi_) : "v"((Q).w), "v"((Q).z), "v"(sel_)); \
        V = (((V) & 8) ? hi_ : lo_) & 0xff;                                           \
    }

#define WALK64(BASE, CUR, PRE, POST)                                                  \
    {                                                                                 \
        uint4 m_[8];                                                                  \
        _Pragma("unroll") for (int z_ = 0; z_ < 8; ++z_)                              \
            m_[z_] = *(const uint4*)((BASE) + (63 - z_) * 16);                        \
        for (int r_ = 63; r_ >= 15; r_ -= 8) {                                        \
            uint4 n_[8];                                                              \
            _Pragma("unroll") for (int z_ = 0; z_ < 8; ++z_)                          \
                n_[z_] = *(const uint4*)((BASE) + (r_ - 8 - z_) * 16);                \
            _Pragma("unroll") for (int z_ = 0; z_ < 8; ++z_) {                        \
                PRE(r_ - z_, CUR) PERMSEL(CUR, m_[z_]) POST(r_ - z_, CUR)             \
            }                                                                         \
            _Pragma("unroll") for (int z_ = 0; z_ < 8; ++z_) m_[z_] = n_[z_];         \
        }                                                                             \
        _Pragma("unroll") for (int z_ = 0; z_ < 8; ++z_) {                            \
            PRE(7 - z_, CUR) PERMSEL(CUR, m_[z_]) POST(7 - z_, CUR)                   \
        }                                                                             \
    }

// Nibble-packed map application: row = u64 of 16 nibbles, next = (row>>4*cur)&15.
#define NIBHOP(V, Q) (V) = (int)(((Q) >> ((unsigned)(V) << 2)) & 15ull);

#define NWALK64(BASE, CUR, POST)                                                      \
    {                                                                                 \
        const unsigned long long* bb_ = (BASE);                                       \
        unsigned long long m_[8];                                                     \
        _Pragma("unroll") for (int z_ = 0; z_ < 8; ++z_) m_[z_] = bb_[63 - z_];       \
        for (int r_ = 63; r_ >= 15; r_ -= 8) {                                       \
            unsigned long long n_[8];                                                 \
            _Pragma("unroll") for (int z_ = 0; z_ < 8; ++z_) n_[z_] = bb_[r_ - 8 - z_]; \
            _Pragma("unroll") for (int z_ = 0; z_ < 8; ++z_) {                        \
                NIBHOP(CUR, m_[z_]) POST(r_ - z_, CUR)                                \
            }                                                                         \
            _Pragma("unroll") for (int z_ = 0; z_ < 8; ++z_) m_[z_] = n_[z_];         \
        }                                                                             \
        _Pragma("unroll") for (int z_ = 0; z_ < 8; ++z_) {                            \
            NIBHOP(CUR, m_[z_]) POST(7 - z_, CUR)                                     \
        }                                                                             \
    }

#define NOPX(r, c)
#define EBL_PRE(r, c) eb[r] = (unsigned char)(c);
#define OUT_POST(r, c) ob[r] = (c);

// ---------------------------------------------------------------------------
// k_main: fwd + psi + chunk maps + backtrace, fully fused. 2 batches/block.
// Wave 0 (g<2): Viterbi chains -> LDS delta double-buffer.
// Waves 1,2: psi of chunk p-1 -> nibble-packed pnib (LDS only).
// Wave 3 (32 lanes): nibble map-walk of chunk p-2 -> Ml (LDS).
// Tail: argmax + boundary chain (byte WALK64 over Ml) + 128 chunk walks
// writing the path straight to out. Zero intermediate global traffic.
__global__ __launch_bounds__(256) void k_main(const float* __restrict__ Epad,
                                              const float* __restrict__ E0,
                                              const float* __restrict__ logA,
                                              const float* __restrict__ logAT,
                                              int* __restrict__ out) {
    __shared__ __align__(16) float dbuf[2][2][16][68];   // 17408 B
    __shared__ unsigned long long pnib[2][64 * 65];      // 66560 B (pitch 65: bank spread)
    __shared__ uint4 Mlv[2][64];                         // 2048 B
    __shared__ unsigned char Ebl[2][64];                 // 128 B
    __shared__ float carry_l[2][16];                     // 128 B
    const int tid = threadIdx.x;
    const int wave = tid >> 6;
    const int blk = blockIdx.x;

    if (wave == 0) {
        asm volatile("s_setprio 3");
        const int j = tid & 15, g = tid >> 4;  // active g<2
        float a[16];
        float d = 0.f;
        float4 q0, q1, q2, q3;
        const float4* ep4 = nullptr;
        if (g < 2) {
            int b = blk * 2 + g;
            a[0] = logA[j * 16 + j];
#define LOADA(K) { int sk = DPP_ROR0(K, j); a[K] = logA[sk * 16 + j]; }
            LOADA(1)  LOADA(2)  LOADA(3)  LOADA(4)  LOADA(5)
            LOADA(6)  LOADA(7)  LOADA(8)  LOADA(9)  LOADA(10)
            LOADA(11) LOADA(12) LOADA(13) LOADA(14) LOADA(15)
#undef LOADA
            ep4 = (const float4*)(Epad + (size_t)b * T_LEN);
            d = __fadd_rn(logA[j], E0[b]);   // delta0
            q0 = ep4[0]; q1 = ep4[1]; q2 = ep4[2]; q3 = ep4[3];
        }
        for (int p = 0; p < 66; ++p) {
            __syncthreads();
            if (p < 64 && g < 2) {
                float* db = &dbuf[p & 1][g][j][0];
                db[64] = d;                   // delta at t = 64p
                const float4* epc = ep4 + 16 * p;
                if (p < 63) {
#pragma clang loop unroll(disable)
                    for (int ii = 0; ii < 4; ++ii) {
                        GRP4(q0, ii * 16 + 0)  q0 = epc[(ii + 1) * 4 + 0];
                        GRP4(q1, ii * 16 + 4)  q1 = epc[(ii + 1) * 4 + 1];
                        GRP4(q2, ii * 16 + 8)  q2 = epc[(ii + 1) * 4 + 2];
                        GRP4(q3, ii * 16 + 12) q3 = epc[(ii + 1) * 4 + 3];
                    }
                } else {
#pragma clang loop unroll(disable)
                    for (int ii = 0; ii < 3; ++ii) {
                        GRP4(q0, ii * 16 + 0)  q0 = epc[(ii + 1) * 4 + 0];
                        GRP4(q1, ii * 16 + 4)  q1 = epc[(ii + 1) * 4 + 1];
                        GRP4(q2, ii * 16 + 8)  q2 = epc[(ii + 1) * 4 + 2];
                        GRP4(q3, ii * 16 + 12) q3 = epc[(ii + 1) * 4 + 3];
                    }
                    GRP4(q0, 48) GRP4(q1, 52) GRP4(q2, 56)      // t=4081..4092
                    STEPC(q3.x) db[60] = d;                      // t=4093
                    STEPC(q3.y) db[61] = d;                      // t=4094
                    STEPC(q3.z) db[62] = d;                      // t=4095
                }
            }
        }
        if (g < 2) carry_l[g][j] = d;
    } else if (wave <= 2) {
        const int g2 = wave - 1;
        const int r = tid & 63;
        for (int p = 0; p < 66; ++p) {
            __syncthreads();
            const int c = p - 1;
            if (c >= 0 && c < 64) {
                const int t2 = 64 * c + 1 + r;
                if (t2 <= T_LEN - 1) {
                    const int q = c & 1;
                    const int rs = (r == 0) ? 64 : (r - 1);
                    float dd[16];
#pragma unroll
                    for (int i = 0; i < 16; ++i) dd[i] = dbuf[q][g2][i][rs];
                    unsigned long long pk = 0ull;
#pragma clang loop unroll(disable)
                    for (int jj = 0; jj < 16; ++jj) {
                        const float* col = logAT + (jj << 4);   // wave-uniform
                        float best = __fadd_rn(dd[0], col[0]);
                        int arg = 0;
#pragma unroll
                        for (int i = 1; i < 16; ++i) {
                            float s = __fadd_rn(dd[i], col[i]);
                            if (s > best) arg = i;  // first-wins tie rule
                            best = fmaxf(best, s);
                        }
                        pk |= (unsigned long long)arg << (jj * 4);
                    }
                    pnib[g2][c * 65 + r] = pk;
                } else {  // c==63, r==63: t=4096 absent -> identity map
                    pnib[g2][c * 65 + 63] = 0xFEDCBA9876543210ull;
                }
            }
        }
    } else {
        const int l = tid - 192;
        const int g3 = l >> 4, z = l & 15;
        for (int p = 0; p < 66; ++p) {
            __syncthreads();
            const int c = p - 2;
            if (c >= 0 && l < 32) {
                int cur = z;
                NWALK64(&pnib[g3][c * 65], cur, NOPX)
                ((unsigned char*)&Mlv[g3][c])[z] = (unsigned char)cur;
            }
        }
    }

    // ---- fused backtrace tail (all LDS-resident) ----
    __syncthreads();
    if (tid < 2) {
        const int g = tid;
        float best = carry_l[g][0]; int zT = 0;
#pragma unroll
        for (int i = 1; i < 16; ++i) {
            float s = carry_l[g][i];
            if (s > best) zT = i;
            best = fmaxf(best, s);
        }
        int z = zT;
        unsigned char* eb = &Ebl[g][0];
        WALK64((const unsigned char*)&Mlv[g][0], z, EBL_PRE, NOPX)
    }
    __syncthreads();
    if (tid < 128) {
        const int g = tid >> 6, c = tid & 63;
        int* ob = out + (size_t)(blk * 2 + g) * T_LEN + c * 64;
        int cur = Ebl[g][c];
        NWALK64(&pnib[g][c * 65], cur, OUT_POST)  // chunk63 identity hop writes out[4095]=zT
    }
}

// ---------------------------------------------------------------------------
extern "C" void kernel_launch(void* const* d_in, const int* in_sizes, int n_in,
                              void* d_out, int out_size, void* d_ws, size_t ws_size,
                              hipStream_t stream) {
    (void)in_sizes; (void)n_in; (void)out_size; (void)ws_size;
    const float* x   = (const float*)d_in[0];   // [512][4096] fp32
    const float* hmm = (const float*)d_in[1];   // [64][16][16] fp32 (only [0] used)
    int* out = (int*)d_out;                     // [512][4096] int32

    char* w = (char*)d_ws;
    float* logA  = (float*)w;                                  // 1KB
    float* logAT = (float*)(w + 1024);                         // 1KB
    float* E0    = (float*)(w + 2048);                         // 2KB
    float* Epad  = (float*)(w + 4096);                         // 8.4MB

    hipLaunchKernelGGL(k_emit, dim3((B_SZ * T_LEN / 4) / 256), dim3(256), 0, stream,
                       x, Epad, E0, hmm, logA, logAT);

    hipLaunchKernelGGL(k_main, dim3(B_SZ / 2), dim3(256), 0, stream,
                       Epad, E0, logA, logAT, out);
}